// Round 2
// baseline (80.402 us; speedup 1.0000x reference)
//
#include <hip/hip_runtime.h>

// SingleShotInhibition: out[b,f,hw] = act[b,f,hw] + sum_m filt[m]*act[b,(f+m-13)&511,hw]
// act: [64, 512, 28, 28] fp32, filt: [27] fp32 (center tap == 0).
//
// R2: vectorize to float4 along hw (16 B/lane -> 1 KiB per wave-instruction).
// R1 was 3.9 TB/s with dword accesses; float4 targets the 6.3 TB/s ceiling.
// Each thread owns one hw-quad; each block computes an 8-channel chunk by
// staging the 34-channel float4 window in registers (statically indexed,
// fully unrolled -> no scratch).

#define SSI_SCOPE 27
#define SSI_HALO  13
#define SSI_C     512
#define SSI_HW    784            // 28*28
#define SSI_QPI   196            // hw quads per image (784/4)
#define SSI_CHUNK 8              // output channels per block
#define SSI_NCHNK 64             // 512 / 8
#define SSI_TPB   256
// quad positions total: 64*196 = 12544 = 49 tiles * 256 threads

__global__ __launch_bounds__(256) void ssi_kernel(
    const float4* __restrict__ act,
    const float* __restrict__ filt,
    float4* __restrict__ out)
{
    const int bid   = blockIdx.x;
    const int qtile = bid / SSI_NCHNK;                    // 0..48
    const int ch0   = (bid % SSI_NCHNK) * SSI_CHUNK;

    const int p4 = qtile * SSI_TPB + (int)threadIdx.x;    // < 12544 exactly
    const int b  = p4 / SSI_QPI;
    const int q  = p4 - b * SSI_QPI;

    const float4* __restrict__ base  = act + (size_t)b * (SSI_C * SSI_QPI) + q;
    float4* __restrict__       obase = out + (size_t)b * (SSI_C * SSI_QPI) + q;

    // 27 taps, uniform address -> scalar loads / SGPRs.
    float w[SSI_SCOPE];
#pragma unroll
    for (int m = 0; m < SSI_SCOPE; ++m) w[m] = filt[m];

    // Stage the 34-channel float4 window in registers (compile-time indices).
    float4 v[SSI_CHUNK + SSI_SCOPE - 1];
#pragma unroll
    for (int k = 0; k < SSI_CHUNK + SSI_SCOPE - 1; ++k) {
        const int c = (ch0 - SSI_HALO + k) & (SSI_C - 1);   // circular wrap
        v[k] = base[c * SSI_QPI];
    }

    // 8 outputs x 27 taps x 4 laneswide, fully unrolled.
    // Residual = v[j+13]; w[13]==0 so the tap-13 FMA adds nothing.
#pragma unroll
    for (int j = 0; j < SSI_CHUNK; ++j) {
        float4 acc = v[j + SSI_HALO];
#pragma unroll
        for (int m = 0; m < SSI_SCOPE; ++m) {
            acc.x = fmaf(w[m], v[j + m].x, acc.x);
            acc.y = fmaf(w[m], v[j + m].y, acc.y);
            acc.z = fmaf(w[m], v[j + m].z, acc.z);
            acc.w = fmaf(w[m], v[j + m].w, acc.w);
        }
        obase[(ch0 + j) * SSI_QPI] = acc;
    }
}

extern "C" void kernel_launch(void* const* d_in, const int* in_sizes, int n_in,
                              void* d_out, int out_size, void* d_ws, size_t ws_size,
                              hipStream_t stream) {
    const float4* act  = (const float4*)d_in[0];   // 64*512*28*28 fp32, 16B-aligned
    const float*  filt = (const float*)d_in[1];    // 27 fp32
    float4* out = (float4*)d_out;

    const int qtiles = (64 * SSI_QPI) / SSI_TPB;   // 49
    dim3 grid(qtiles * SSI_NCHNK);                 // 3136 blocks
    dim3 block(SSI_TPB);
    hipLaunchKernelGGL(ssi_kernel, grid, block, 0, stream, act, filt, out);
}

// Round 4
// 50.136 us; speedup vs baseline: 1.6037x; 1.6037x over previous
//
#include <hip/hip_runtime.h>

// SingleShotInhibition: out[b,f,hw] = act[b,f,hw] + sum_m filt[m]*act[b,(f+m-13)&511,hw]
// act: [64, 512, 28, 28] fp32, filt: [27] fp32 (center tap == 0 in the data).
//
// R4 = R3 with native clang vector type (ext_vector_type) so
// __builtin_nontemporal_store accepts it. float4-width (16 B/lane) accesses +
// CHUNK=32 (R1's dedup-friendly traffic) via a rolling 27-deep register
// window: per unrolled step load 1 new channel, emit 1 output -> only
// 27 x 4 = 108 window VGPRs live. nontemporal stores keep the 101 MB write
// stream from evicting the shared input in L2/L3.

typedef float v4f __attribute__((ext_vector_type(4)));

#define SSI_SCOPE 27
#define SSI_HALO  13
#define SSI_C     512
#define SSI_QPI   196            // float4 quads per image-channel (784/4)
#define SSI_CHUNK 32             // output channels per block
#define SSI_NCHNK 16             // 512 / 32
#define SSI_TPB   256
// quad positions total: 64*196 = 12544 = 49 tiles * 256 threads; grid = 49*16 = 784

__global__ __launch_bounds__(256) void ssi_kernel(
    const v4f* __restrict__ act,
    const float* __restrict__ filt,
    v4f* __restrict__ out)
{
    const int bid   = blockIdx.x;
    const int qtile = bid / SSI_NCHNK;
    const int ch0   = (bid % SSI_NCHNK) * SSI_CHUNK;

    const int p4 = qtile * SSI_TPB + (int)threadIdx.x;   // < 12544 exactly
    const int b  = p4 / SSI_QPI;
    const int q  = p4 - b * SSI_QPI;

    const v4f* __restrict__ base  = act + (size_t)b * (SSI_C * SSI_QPI) + q;
    v4f* __restrict__       obase = out + (size_t)b * (SSI_C * SSI_QPI) + q;

    // 27 taps, uniform address -> scalar loads / SGPRs.
    float w[SSI_SCOPE];
#pragma unroll
    for (int m = 0; m < SSI_SCOPE; ++m) w[m] = filt[m];

    // Rolling window: slot(c) = (c - ch0 + 13) % 27, all indices compile-time.
    v4f v[SSI_SCOPE];

    // Prologue: channels ch0-13 .. ch0+12 -> slots 0..25.
#pragma unroll
    for (int i = 0; i < SSI_SCOPE - 1; ++i) {
        const int c = (ch0 - SSI_HALO + i) & (SSI_C - 1);
        v[i] = base[c * SSI_QPI];
    }

    // Main: per step j, load channel ch0+13+j (slot (26+j)%27, overwriting
    // channel ch0+j-14 which no output >= j needs), then emit output ch0+j.
#pragma unroll
    for (int j = 0; j < SSI_CHUNK; ++j) {
        const int cl = (ch0 + SSI_HALO + j) & (SSI_C - 1);
        v[(SSI_SCOPE - 1 + j) % SSI_SCOPE] = base[cl * SSI_QPI];

        v4f acc = v[(j + SSI_HALO) % SSI_SCOPE];         // residual (center)
#pragma unroll
        for (int m = 0; m < SSI_SCOPE; ++m) {
            if (m == SSI_HALO) continue;                 // w[13] == 0 for this input
            const v4f x = v[(j + m) % SSI_SCOPE];
            acc.x = fmaf(w[m], x.x, acc.x);
            acc.y = fmaf(w[m], x.y, acc.y);
            acc.z = fmaf(w[m], x.z, acc.z);
            acc.w = fmaf(w[m], x.w, acc.w);
        }
        __builtin_nontemporal_store(acc, &obase[(ch0 + j) * SSI_QPI]);
    }
}

extern "C" void kernel_launch(void* const* d_in, const int* in_sizes, int n_in,
                              void* d_out, int out_size, void* d_ws, size_t ws_size,
                              hipStream_t stream) {
    const v4f*   act  = (const v4f*)d_in[0];   // 64*512*28*28 fp32, 16B-aligned
    const float* filt = (const float*)d_in[1]; // 27 fp32
    v4f* out = (v4f*)d_out;

    const int qtiles = (64 * SSI_QPI) / SSI_TPB;   // 49
    dim3 grid(qtiles * SSI_NCHNK);                 // 784 blocks
    dim3 block(SSI_TPB);
    hipLaunchKernelGGL(ssi_kernel, grid, block, 0, stream, act, filt, out);
}

// Round 5
// 47.646 us; speedup vs baseline: 1.6875x; 1.0522x over previous
//
#include <hip/hip_runtime.h>

// SingleShotInhibition: out[b,f,hw] = act[b,f,hw] + sum_m filt[m]*act[b,(f+m-13)&511,hw]
// act: [64, 512, 28, 28] fp32, filt: [27] fp32 (center tap == 0 in the data).
//
// R5: attack latency-bound regime (Little's law). R1/R4 both ~3.9 TB/s with
// VGPR counts that leave ZERO run-ahead headroom for the rolling-window loads
// (R1: 36 VGPR = window+addr exactly). Here: float2 width (512 B/wave-instr),
// 24.5 waves/CU available (1568 blocks), and __launch_bounds__(256,4) to give
// the allocator a 128-VGPR budget -> ~29 loads of run-ahead per wave.
// Traffic stays minimal (CHUNK=32 -> 1.81x L2 halo, dedup'd at L3).

typedef float v2f __attribute__((ext_vector_type(2)));

#define SSI_SCOPE 27
#define SSI_HALO  13
#define SSI_C     512
#define SSI_QPI   392            // float2 pairs per image-channel (784/2)
#define SSI_CHUNK 32             // output channels per block
#define SSI_NCHNK 16             // 512 / 32
#define SSI_TPB   256
// pair positions total: 64*392 = 25088 = 98 tiles * 256 threads; grid = 98*16 = 1568

__global__ __launch_bounds__(256, 4) void ssi_kernel(
    const v2f* __restrict__ act,
    const float* __restrict__ filt,
    v2f* __restrict__ out)
{
    const int bid   = blockIdx.x;
    const int qtile = bid / SSI_NCHNK;                   // 0..97
    const int ch0   = (bid % SSI_NCHNK) * SSI_CHUNK;

    const int p2 = qtile * SSI_TPB + (int)threadIdx.x;   // < 25088 exactly
    const int b  = p2 / SSI_QPI;
    const int q  = p2 - b * SSI_QPI;

    const v2f* __restrict__ base  = act + (size_t)b * (SSI_C * SSI_QPI) + q;
    v2f* __restrict__       obase = out + (size_t)b * (SSI_C * SSI_QPI) + q;

    // 27 taps, uniform address -> scalar loads / SGPRs.
    float w[SSI_SCOPE];
#pragma unroll
    for (int m = 0; m < SSI_SCOPE; ++m) w[m] = filt[m];

    // Rolling window: slot(c) = (c - ch0 + 13) % 27, all indices compile-time.
    // After SROA the slots are SSA values, so the compiler can run loads
    // ahead of the FMA chain as far as the 128-VGPR budget allows.
    v2f v[SSI_SCOPE];

    // Prologue: channels ch0-13 .. ch0+12 -> slots 0..25.
#pragma unroll
    for (int i = 0; i < SSI_SCOPE - 1; ++i) {
        const int c = (ch0 - SSI_HALO + i) & (SSI_C - 1);
        v[i] = base[c * SSI_QPI];
    }

    // Main: per step j, load channel ch0+13+j, then emit output ch0+j.
#pragma unroll
    for (int j = 0; j < SSI_CHUNK; ++j) {
        const int cl = (ch0 + SSI_HALO + j) & (SSI_C - 1);
        v[(SSI_SCOPE - 1 + j) % SSI_SCOPE] = base[cl * SSI_QPI];

        v2f acc = v[(j + SSI_HALO) % SSI_SCOPE];         // residual (center)
#pragma unroll
        for (int m = 0; m < SSI_SCOPE; ++m) {
            if (m == SSI_HALO) continue;                 // w[13] == 0 for this input
            const v2f x = v[(j + m) % SSI_SCOPE];
            acc.x = fmaf(w[m], x.x, acc.x);
            acc.y = fmaf(w[m], x.y, acc.y);
        }
        __builtin_nontemporal_store(acc, &obase[(ch0 + j) * SSI_QPI]);
    }
}

extern "C" void kernel_launch(void* const* d_in, const int* in_sizes, int n_in,
                              void* d_out, int out_size, void* d_ws, size_t ws_size,
                              hipStream_t stream) {
    const v2f*   act  = (const v2f*)d_in[0];   // 64*512*28*28 fp32
    const float* filt = (const float*)d_in[1]; // 27 fp32
    v2f* out = (v2f*)d_out;

    const int qtiles = (64 * SSI_QPI) / SSI_TPB;   // 98
    dim3 grid(qtiles * SSI_NCHNK);                 // 1568 blocks
    dim3 block(SSI_TPB);
    hipLaunchKernelGGL(ssi_kernel, grid, block, 0, stream, act, filt, out);
}